// Round 2
// baseline (4885.074 us; speedup 1.0000x reference)
//
#include <hip/hip_runtime.h>

#define EPSV 1e-5f

static inline int cdiv(int a, int b) { return (a + b - 1) / b; }

__global__ void zero_kernel(float* __restrict__ p, int n) {
  int i = blockIdx.x * blockDim.x + threadIdx.x;
  if (i < n) p[i] = 0.f;
}

// Thread = one output row (or 1/SPLIT of its couts). Register-blocked over COT
// couts: each gathered feature element is reused COT times. Weight indices are
// wave-uniform -> scalar loads. BN sum/sumsq reduced by wave butterfly, one
// global atomic per wave per channel.
template<int CI, int CO, int SPLIT>
__global__ __launch_bounds__(256) void conv_kernel(
    const float* __restrict__ f, const int* __restrict__ nbr,
    const float* __restrict__ w, float* __restrict__ y,
    float* __restrict__ stats, int nout) {
  constexpr int COT = CO / SPLIT;
  const int t = blockIdx.x * 256 + threadIdx.x;
  const int n = t / SPLIT;
  const int part = t % SPLIT;         // == lane % SPLIT
  const int ob = part * COT;
  const int lane = threadIdx.x & 63;

  float acc[COT];
#pragma unroll
  for (int o = 0; o < COT; ++o) acc[o] = 0.f;

  if (n < nout) {
    const int* nb = nbr + (long)n * 27;
#pragma unroll 1
    for (int k = 0; k < 27; ++k) {
      int idx = nb[k];
      if (idx >= 0) {
        const float4* fr = (const float4*)(f + (long)idx * CI);
#pragma unroll
        for (int c4 = 0; c4 < CI / 4; ++c4) {
          float4 fv = fr[c4];
          const float* wr = w + ((long)k * CI + c4 * 4) * CO + ob;
#pragma unroll
          for (int j = 0; j < 4; ++j) {
            float fc = (j == 0) ? fv.x : (j == 1) ? fv.y : (j == 2) ? fv.z : fv.w;
#pragma unroll
            for (int o = 0; o < COT; ++o)
              acc[o] = fmaf(fc, wr[(long)j * CO + o], acc[o]);
          }
        }
      }
    }
    // vector store of this thread's couts
    float4* yr = (float4*)(y + (long)n * CO + ob);
#pragma unroll
    for (int o4 = 0; o4 < COT / 4; ++o4)
      yr[o4] = make_float4(acc[4 * o4], acc[4 * o4 + 1], acc[4 * o4 + 2], acc[4 * o4 + 3]);
  }

  // BN statistics: butterfly over lanes sharing the same part, then one atomic
  // per wave per channel.
#pragma unroll
  for (int o = 0; o < COT; ++o) {
    float v = (n < nout) ? acc[o] : 0.f;
    float q = v * v;
#pragma unroll
    for (int off = 32; off >= SPLIT; off >>= 1) {
      v += __shfl_xor(v, off);
      q += __shfl_xor(q, off);
    }
    if (lane < SPLIT) {  // lane == part here
      atomicAdd(&stats[lane * COT + o], v);
      atomicAdd(&stats[64 + lane * COT + o], q);
    }
  }
}

// Applies training-mode BN (+ ReLU) and optional residual add (skip != nullptr).
template<int CO>
__global__ __launch_bounds__(256) void bn_relu_kernel(
    const float* __restrict__ y, const float* __restrict__ stats,
    const float* __restrict__ g, const float* __restrict__ b,
    const float* __restrict__ skip, float* __restrict__ out, int nout) {
  int i = blockIdx.x * blockDim.x + threadIdx.x;
  int total = nout * CO;
  if (i >= total) return;
  int o = i % CO;
  float inv_n = 1.f / (float)nout;
  float mu = stats[o] * inv_n;
  float var = stats[64 + o] * inv_n - mu * mu;
  float v = (y[i] - mu) * rsqrtf(var + EPSV) * g[o] + b[o];
  v = fmaxf(v, 0.f);
  if (skip) v += skip[i];
  out[i] = v;
}

// out[n,j] = sum_c x[n,c] * w[j,c]   (8x8)
__global__ __launch_bounds__(256) void linear_kernel(
    const float* __restrict__ x, const float* __restrict__ w,
    float* __restrict__ out, int n0) {
  int i = blockIdx.x * blockDim.x + threadIdx.x;
  if (i >= n0 * 8) return;
  int n = i >> 3, j = i & 7;
  const float* xr = x + n * 8;
  const float* wr = w + j * 8;
  float acc = 0.f;
#pragma unroll
  for (int c = 0; c < 8; ++c) acc = fmaf(xr[c], wr[c], acc);
  out[i] = acc;
}

extern "C" void kernel_launch(void* const* d_in, const int* in_sizes, int n_in,
                              void* d_out, int out_size, void* d_ws, size_t ws_size,
                              hipStream_t stream) {
  // ---- inputs (setup_inputs dict order) ----
  const float* feats   = (const float*)d_in[0];
  const int* nbr0      = (const int*)d_in[1];
  const int* nbr_d01   = (const int*)d_in[2];
  const int* nbr1      = (const int*)d_in[3];
  const int* nbr_d12   = (const int*)d_in[4];
  const int* nbr2      = (const int*)d_in[5];
  const int* nbr_d23   = (const int*)d_in[6];
  const int* nbr3      = (const int*)d_in[7];
  const int* nbr_u32   = (const int*)d_in[8];
  const int* nbr_u21   = (const int*)d_in[9];
  const int* nbr_u10   = (const int*)d_in[10];
  const float* w[10];
  const float* g[10];
  const float* b[10];
  for (int i = 0; i < 10; ++i) {
    w[i] = (const float*)d_in[11 + 3 * i];
    g[i] = (const float*)d_in[12 + 3 * i];
    b[i] = (const float*)d_in[13 + 3 * i];
  }
  const float* lin_w = (const float*)d_in[41];

  const int N0 = in_sizes[0] / 16;
  const int N1 = in_sizes[2] / 27;
  const int N2 = in_sizes[4] / 27;
  const int N3 = in_sizes[6] / 27;

  // ---- workspace layout (floats) ----
  float* ws    = (float*)d_ws;
  float* stats = ws;                       // 10 slots x 128 floats
  float* c0f   = stats + 10 * 128;         // N0*8   (skip, kept)
  float* t1    = c0f + (size_t)N0 * 8;     // N1*16
  float* c2f   = t1 + (size_t)N1 * 16;     // N1*16  (skip, kept)
  float* t2    = c2f + (size_t)N1 * 16;    // N2*32
  float* c4f   = t2 + (size_t)N2 * 32;     // N2*32  (skip, kept)
  float* t3    = c4f + (size_t)N2 * 32;    // N3*64
  float* t4    = t3 + (size_t)N3 * 64;     // N3*64
  float* t5    = t2;                       // reuse (t2 dead after conv4)
  float* t6    = t1;                       // reuse (t1 dead after conv2)

  float* out0 = (float*)d_out;                  // linear output; also conv9 y staging
  float* x0   = (float*)d_out + (size_t)N0 * 8; // second output: x itself

  zero_kernel<<<cdiv(10 * 128, 256), 256, 0, stream>>>(stats, 10 * 128);

  // conv0: 16->8 @ N0
  conv_kernel<16, 8, 1><<<cdiv(N0, 256), 256, 0, stream>>>(feats, nbr0, w[0], c0f, stats + 0 * 128, N0);
  bn_relu_kernel<8><<<cdiv(N0 * 8, 256), 256, 0, stream>>>(c0f, stats + 0 * 128, g[0], b[0], nullptr, c0f, N0);

  // conv1: 8->16 down to N1
  conv_kernel<8, 16, 1><<<cdiv(N1, 256), 256, 0, stream>>>(c0f, nbr_d01, w[1], t1, stats + 1 * 128, N1);
  bn_relu_kernel<16><<<cdiv(N1 * 16, 256), 256, 0, stream>>>(t1, stats + 1 * 128, g[1], b[1], nullptr, t1, N1);

  // conv2: 16->16 @ N1
  conv_kernel<16, 16, 1><<<cdiv(N1, 256), 256, 0, stream>>>(t1, nbr1, w[2], c2f, stats + 2 * 128, N1);
  bn_relu_kernel<16><<<cdiv(N1 * 16, 256), 256, 0, stream>>>(c2f, stats + 2 * 128, g[2], b[2], nullptr, c2f, N1);

  // conv3: 16->32 down to N2
  conv_kernel<16, 32, 1><<<cdiv(N2, 256), 256, 0, stream>>>(c2f, nbr_d12, w[3], t2, stats + 3 * 128, N2);
  bn_relu_kernel<32><<<cdiv(N2 * 32, 256), 256, 0, stream>>>(t2, stats + 3 * 128, g[3], b[3], nullptr, t2, N2);

  // conv4: 32->32 @ N2
  conv_kernel<32, 32, 1><<<cdiv(N2, 256), 256, 0, stream>>>(t2, nbr2, w[4], c4f, stats + 4 * 128, N2);
  bn_relu_kernel<32><<<cdiv(N2 * 32, 256), 256, 0, stream>>>(c4f, stats + 4 * 128, g[4], b[4], nullptr, c4f, N2);

  // conv5: 32->64 down to N3 (SPLIT=2: 32 accs/thread)
  conv_kernel<32, 64, 2><<<cdiv(N3 * 2, 256), 256, 0, stream>>>(c4f, nbr_d23, w[5], t3, stats + 5 * 128, N3);
  bn_relu_kernel<64><<<cdiv(N3 * 64, 256), 256, 0, stream>>>(t3, stats + 5 * 128, g[5], b[5], nullptr, t3, N3);

  // conv6: 64->64 @ N3 (SPLIT=2)
  conv_kernel<64, 64, 2><<<cdiv(N3 * 2, 256), 256, 0, stream>>>(t3, nbr3, w[6], t4, stats + 6 * 128, N3);
  bn_relu_kernel<64><<<cdiv(N3 * 64, 256), 256, 0, stream>>>(t4, stats + 6 * 128, g[6], b[6], nullptr, t4, N3);

  // conv7: 64->32 up to N2, then x2 = c4f + relu(bn(y))
  conv_kernel<64, 32, 1><<<cdiv(N2, 256), 256, 0, stream>>>(t4, nbr_u32, w[7], t5, stats + 7 * 128, N2);
  bn_relu_kernel<32><<<cdiv(N2 * 32, 256), 256, 0, stream>>>(t5, stats + 7 * 128, g[7], b[7], c4f, t5, N2);

  // conv8: 32->16 up to N1, then x1 = c2f + relu(bn(y))
  conv_kernel<32, 16, 1><<<cdiv(N1, 256), 256, 0, stream>>>(t5, nbr_u21, w[8], t6, stats + 8 * 128, N1);
  bn_relu_kernel<16><<<cdiv(N1 * 16, 256), 256, 0, stream>>>(t6, stats + 8 * 128, g[8], b[8], c2f, t6, N1);

  // conv9: 16->8 up to N0, then x0 = c0f + relu(bn(y))
  // raw y staged in out0 (overwritten by linear kernel afterwards)
  conv_kernel<16, 8, 1><<<cdiv(N0, 256), 256, 0, stream>>>(t6, nbr_u10, w[9], out0, stats + 9 * 128, N0);
  bn_relu_kernel<8><<<cdiv(N0 * 8, 256), 256, 0, stream>>>(out0, stats + 9 * 128, g[9], b[9], c0f, x0, N0);

  // final linear: out0 = x0 @ lin_w.T
  linear_kernel<<<cdiv(N0 * 8, 256), 256, 0, stream>>>(x0, lin_w, out0, N0);
}

// Round 3
// 995.423 us; speedup vs baseline: 4.9075x; 4.9075x over previous
//
#include <hip/hip_runtime.h>

#define EPSV 1e-5f

static inline int cdiv(int a, int b) { return (a + b - 1) / b; }
static inline long lcdiv(long a, long b) { return (a + b - 1) / b; }

__global__ void zero_kernel(float* __restrict__ p, int n) {
  int i = blockIdx.x * blockDim.x + threadIdx.x;
  if (i < n) p[i] = 0.f;
}

// ---- shared BN-stats reduction: wave butterfly -> LDS -> 1 global atomic/block ----
template<int CO, int COT>
__device__ inline void bn_stats_reduce(float (&acc)[COT], float* stats, int lane) {
  constexpr int TPR = CO / COT;
  __shared__ float s_red[2 * CO];
  for (int i = threadIdx.x; i < 2 * CO; i += 256) s_red[i] = 0.f;
  __syncthreads();
#pragma unroll
  for (int o = 0; o < COT; ++o) {
    float v = acc[o];
    float q = v * v;
#pragma unroll
    for (int off = 32; off >= TPR; off >>= 1) {
      v += __shfl_xor(v, off);
      q += __shfl_xor(q, off);
    }
    if (lane < TPR) {
      atomicAdd(&s_red[lane * COT + o], v);
      atomicAdd(&s_red[CO + lane * COT + o], q);
    }
  }
  __syncthreads();
  if (threadIdx.x < CO) {
    atomicAdd(&stats[threadIdx.x], s_red[threadIdx.x]);
    atomicAdd(&stats[64 + threadIdx.x], s_red[CO + threadIdx.x]);
  }
}

// ---- full-27 k-loop (dense-ish neighbor tables, levels 1-3) ----
// Thread = (row, COT-slice of couts). Wave-uniform weight loads (scalar).
// 1-deep software pipeline on the gathered feature row.
template<int CI, int CO, int COT>
__global__ __launch_bounds__(256) void conv_full(
    const float* __restrict__ f, const int* __restrict__ nbr,
    const float* __restrict__ w, float* __restrict__ y,
    float* __restrict__ stats, int nout) {
  constexpr int TPR = CO / COT;
  constexpr int F4 = CI / 4;
  const long t = (long)blockIdx.x * 256 + threadIdx.x;
  const int n = (int)(t / TPR);
  const int part = (int)(t % TPR);
  const int ob = part * COT;
  const int lane = threadIdx.x & 63;

  float acc[COT];
#pragma unroll
  for (int o = 0; o < COT; ++o) acc[o] = 0.f;

  if (n < nout) {
    const int* nb = nbr + (long)n * 27;
    float4 buf[F4];
    int id0 = nb[0];
    bool valid = id0 >= 0;
    {
      const float4* fr = (const float4*)(f + (long)max(id0, 0) * CI);
#pragma unroll
      for (int c = 0; c < F4; ++c) buf[c] = fr[c];
    }
#pragma unroll 1
    for (int k = 0; k < 27; ++k) {
      float4 nbuf[F4];
      bool nvalid = false;
      if (k + 1 < 27) {
        int idn = nb[k + 1];
        nvalid = idn >= 0;
        const float4* fr = (const float4*)(f + (long)max(idn, 0) * CI);
#pragma unroll
        for (int c = 0; c < F4; ++c) nbuf[c] = fr[c];
      }
      if (valid) {
        const float* wk = w + (long)k * CI * CO + ob;
#pragma unroll
        for (int c = 0; c < F4; ++c) {
          float4 fv = buf[c];
#pragma unroll
          for (int j = 0; j < 4; ++j) {
            float fc = (j == 0) ? fv.x : (j == 1) ? fv.y : (j == 2) ? fv.z : fv.w;
            const float* wr = wk + (long)(c * 4 + j) * CO;
#pragma unroll
            for (int o = 0; o < COT; ++o)
              acc[o] = fmaf(fc, wr[o], acc[o]);
          }
        }
      }
      valid = nvalid;
#pragma unroll
      for (int c = 0; c < F4; ++c) buf[c] = nbuf[c];
    }
    float4* yr = (float4*)(y + (long)n * CO + ob);
#pragma unroll
    for (int o4 = 0; o4 < COT / 4; ++o4)
      yr[o4] = make_float4(acc[4 * o4], acc[4 * o4 + 1], acc[4 * o4 + 2], acc[4 * o4 + 3]);
  }
  bn_stats_reduce<CO, COT>(acc, stats, lane);
}

// ---- compacted k-loop (sparse neighbor tables: level-0 convs + up-convs) ----
// Per-lane bitmask of valid ks; wave runs only max-popcount iterations.
// Weights become per-lane gathers (k divergent) but stay L1/L2-hot.
template<int CI, int CO, int COT>
__global__ __launch_bounds__(256) void conv_compact(
    const float* __restrict__ f, const int* __restrict__ nbr,
    const float* __restrict__ w, float* __restrict__ y,
    float* __restrict__ stats, int nout) {
  constexpr int TPR = CO / COT;
  constexpr int F4 = CI / 4;
  const long t = (long)blockIdx.x * 256 + threadIdx.x;
  const int n = (int)(t / TPR);
  const int part = (int)(t % TPR);
  const int ob = part * COT;
  const int lane = threadIdx.x & 63;

  float acc[COT];
#pragma unroll
  for (int o = 0; o < COT; ++o) acc[o] = 0.f;

  if (n < nout) {
    const int* nb = nbr + (long)n * 27;
    unsigned m = 0;
#pragma unroll
    for (int k = 0; k < 27; ++k) m |= (nb[k] >= 0 ? 1u : 0u) << k;

    int k = -1, idx = 0;
    float4 buf[F4];
    if (m) {
      k = __builtin_ctz(m); m &= m - 1;
      idx = nb[k];
      const float4* fr = (const float4*)(f + (long)idx * CI);
#pragma unroll
      for (int c = 0; c < F4; ++c) buf[c] = fr[c];
    }
    while (k >= 0) {
      // prefetch next valid neighbor's features
      int k2 = -1;
      float4 nbuf[F4];
      if (m) {
        k2 = __builtin_ctz(m); m &= m - 1;
        int idx2 = nb[k2];
        const float4* fr = (const float4*)(f + (long)idx2 * CI);
#pragma unroll
        for (int c = 0; c < F4; ++c) nbuf[c] = fr[c];
      }
      const float* wk = w + (long)k * CI * CO + ob;
#pragma unroll
      for (int c = 0; c < F4; ++c) {
        float4 fv = buf[c];
#pragma unroll
        for (int j = 0; j < 4; ++j) {
          float fc = (j == 0) ? fv.x : (j == 1) ? fv.y : (j == 2) ? fv.z : fv.w;
          const float* wr = wk + (long)(c * 4 + j) * CO;
#pragma unroll
          for (int o = 0; o < COT; ++o)
            acc[o] = fmaf(fc, wr[o], acc[o]);
        }
      }
      k = k2;
#pragma unroll
      for (int c = 0; c < F4; ++c) buf[c] = nbuf[c];
    }
    float4* yr = (float4*)(y + (long)n * CO + ob);
#pragma unroll
    for (int o4 = 0; o4 < COT / 4; ++o4)
      yr[o4] = make_float4(acc[4 * o4], acc[4 * o4 + 1], acc[4 * o4 + 2], acc[4 * o4 + 3]);
  }
  bn_stats_reduce<CO, COT>(acc, stats, lane);
}

// Applies training-mode BN (+ ReLU) and optional residual add (skip != nullptr).
template<int CO>
__global__ __launch_bounds__(256) void bn_relu_kernel(
    const float* __restrict__ y, const float* __restrict__ stats,
    const float* __restrict__ g, const float* __restrict__ b,
    const float* __restrict__ skip, float* __restrict__ out, int nout) {
  int i = blockIdx.x * blockDim.x + threadIdx.x;
  int total = nout * CO;
  if (i >= total) return;
  int o = i % CO;
  float inv_n = 1.f / (float)nout;
  float mu = stats[o] * inv_n;
  float var = stats[64 + o] * inv_n - mu * mu;
  float v = (y[i] - mu) * rsqrtf(var + EPSV) * g[o] + b[o];
  v = fmaxf(v, 0.f);
  if (skip) v += skip[i];
  out[i] = v;
}

// out[n,j] = sum_c x[n,c] * w[j,c]   (8x8)
__global__ __launch_bounds__(256) void linear_kernel(
    const float* __restrict__ x, const float* __restrict__ w,
    float* __restrict__ out, int n0) {
  int i = blockIdx.x * blockDim.x + threadIdx.x;
  if (i >= n0 * 8) return;
  int n = i >> 3, j = i & 7;
  const float* xr = x + n * 8;
  const float* wr = w + j * 8;
  float acc = 0.f;
#pragma unroll
  for (int c = 0; c < 8; ++c) acc = fmaf(xr[c], wr[c], acc);
  out[i] = acc;
}

extern "C" void kernel_launch(void* const* d_in, const int* in_sizes, int n_in,
                              void* d_out, int out_size, void* d_ws, size_t ws_size,
                              hipStream_t stream) {
  // ---- inputs (setup_inputs dict order) ----
  const float* feats   = (const float*)d_in[0];
  const int* nbr0      = (const int*)d_in[1];
  const int* nbr_d01   = (const int*)d_in[2];
  const int* nbr1      = (const int*)d_in[3];
  const int* nbr_d12   = (const int*)d_in[4];
  const int* nbr2      = (const int*)d_in[5];
  const int* nbr_d23   = (const int*)d_in[6];
  const int* nbr3      = (const int*)d_in[7];
  const int* nbr_u32   = (const int*)d_in[8];
  const int* nbr_u21   = (const int*)d_in[9];
  const int* nbr_u10   = (const int*)d_in[10];
  const float* w[10];
  const float* g[10];
  const float* b[10];
  for (int i = 0; i < 10; ++i) {
    w[i] = (const float*)d_in[11 + 3 * i];
    g[i] = (const float*)d_in[12 + 3 * i];
    b[i] = (const float*)d_in[13 + 3 * i];
  }
  const float* lin_w = (const float*)d_in[41];

  const int N0 = in_sizes[0] / 16;
  const int N1 = in_sizes[2] / 27;
  const int N2 = in_sizes[4] / 27;
  const int N3 = in_sizes[6] / 27;

  // ---- workspace layout (floats) ----
  float* ws    = (float*)d_ws;
  float* stats = ws;                       // 10 slots x 128 floats
  float* c0f   = stats + 10 * 128;         // N0*8   (skip, kept)
  float* t1    = c0f + (size_t)N0 * 8;     // N1*16
  float* c2f   = t1 + (size_t)N1 * 16;     // N1*16  (skip, kept)
  float* t2    = c2f + (size_t)N1 * 16;    // N2*32
  float* c4f   = t2 + (size_t)N2 * 32;     // N2*32  (skip, kept)
  float* t3    = c4f + (size_t)N2 * 32;    // N3*64
  float* t4    = t3 + (size_t)N3 * 64;     // N3*64
  float* t5    = t2;                       // reuse (t2 dead after conv4)
  float* t6    = t1;                       // reuse (t1 dead after conv2)

  float* out0 = (float*)d_out;                  // linear output; also conv9 y staging
  float* x0   = (float*)d_out + (size_t)N0 * 8; // second output: x itself

  zero_kernel<<<cdiv(10 * 128, 256), 256, 0, stream>>>(stats, 10 * 128);

  // conv0: 16->8 @ N0 (level-0, ~12% valid) -> compact, COT=8 (TPR=1)
  conv_compact<16, 8, 8><<<(int)lcdiv((long)N0 * 1, 256), 256, 0, stream>>>(
      feats, nbr0, w[0], c0f, stats + 0 * 128, N0);
  bn_relu_kernel<8><<<cdiv(N0 * 8, 256), 256, 0, stream>>>(c0f, stats + 0 * 128, g[0], b[0], nullptr, c0f, N0);

  // conv1: 8->16 down to N1 (gathers level-0, ~12% valid) -> compact, COT=16
  conv_compact<8, 16, 16><<<(int)lcdiv((long)N1 * 1, 256), 256, 0, stream>>>(
      c0f, nbr_d01, w[1], t1, stats + 1 * 128, N1);
  bn_relu_kernel<16><<<cdiv(N1 * 16, 256), 256, 0, stream>>>(t1, stats + 1 * 128, g[1], b[1], nullptr, t1, N1);

  // conv2: 16->16 @ N1 (~64% valid) -> full, COT=16 (TPR=1)
  conv_full<16, 16, 16><<<(int)lcdiv((long)N1 * 1, 256), 256, 0, stream>>>(
      t1, nbr1, w[2], c2f, stats + 2 * 128, N1);
  bn_relu_kernel<16><<<cdiv(N1 * 16, 256), 256, 0, stream>>>(c2f, stats + 2 * 128, g[2], b[2], nullptr, c2f, N1);

  // conv3: 16->32 down to N2 (~64% valid) -> full, COT=16 (TPR=2)
  conv_full<16, 32, 16><<<(int)lcdiv((long)N2 * 2, 256), 256, 0, stream>>>(
      c2f, nbr_d12, w[3], t2, stats + 3 * 128, N2);
  bn_relu_kernel<32><<<cdiv(N2 * 32, 256), 256, 0, stream>>>(t2, stats + 3 * 128, g[3], b[3], nullptr, t2, N2);

  // conv4: 32->32 @ N2 (~99% valid) -> full, COT=16 (TPR=2)
  conv_full<32, 32, 16><<<(int)lcdiv((long)N2 * 2, 256), 256, 0, stream>>>(
      t2, nbr2, w[4], c4f, stats + 4 * 128, N2);
  bn_relu_kernel<32><<<cdiv(N2 * 32, 256), 256, 0, stream>>>(c4f, stats + 4 * 128, g[4], b[4], nullptr, c4f, N2);

  // conv5: 32->64 down to N3 (~99% valid) -> full, COT=4 (TPR=16) for parallelism
  conv_full<32, 64, 4><<<(int)lcdiv((long)N3 * 16, 256), 256, 0, stream>>>(
      c4f, nbr_d23, w[5], t3, stats + 5 * 128, N3);
  bn_relu_kernel<64><<<cdiv(N3 * 64, 256), 256, 0, stream>>>(t3, stats + 5 * 128, g[5], b[5], nullptr, t3, N3);

  // conv6: 64->64 @ N3 (100% valid) -> full, COT=4 (TPR=16)
  conv_full<64, 64, 4><<<(int)lcdiv((long)N3 * 16, 256), 256, 0, stream>>>(
      t3, nbr3, w[6], t4, stats + 6 * 128, N3);
  bn_relu_kernel<64><<<cdiv(N3 * 64, 256), 256, 0, stream>>>(t4, stats + 6 * 128, g[6], b[6], nullptr, t4, N3);

  // conv7: 64->32 up to N2 (parity-sparse, ~12% valid) -> compact, COT=8 (TPR=4)
  conv_compact<64, 32, 8><<<(int)lcdiv((long)N2 * 4, 256), 256, 0, stream>>>(
      t4, nbr_u32, w[7], t5, stats + 7 * 128, N2);
  bn_relu_kernel<32><<<cdiv(N2 * 32, 256), 256, 0, stream>>>(t5, stats + 7 * 128, g[7], b[7], c4f, t5, N2);

  // conv8: 32->16 up to N1 (parity-sparse) -> compact, COT=8 (TPR=2)
  conv_compact<32, 16, 8><<<(int)lcdiv((long)N1 * 2, 256), 256, 0, stream>>>(
      t5, nbr_u21, w[8], t6, stats + 8 * 128, N1);
  bn_relu_kernel<16><<<cdiv(N1 * 16, 256), 256, 0, stream>>>(t6, stats + 8 * 128, g[8], b[8], c2f, t6, N1);

  // conv9: 16->8 up to N0 (parity-sparse + 12% occupancy) -> compact, COT=8
  conv_compact<16, 8, 8><<<(int)lcdiv((long)N0 * 1, 256), 256, 0, stream>>>(
      t6, nbr_u10, w[9], out0, stats + 9 * 128, N0);
  bn_relu_kernel<8><<<cdiv(N0 * 8, 256), 256, 0, stream>>>(out0, stats + 9 * 128, g[9], b[9], c0f, x0, N0);

  // final linear: out0 = x0 @ lin_w.T
  linear_kernel<<<cdiv(N0 * 8, 256), 256, 0, stream>>>(x0, lin_w, out0, N0);
}

// Round 4
// 653.202 us; speedup vs baseline: 7.4787x; 1.5239x over previous
//
#include <hip/hip_runtime.h>

#define EPSV 1e-5f

static inline int cdiv(int a, int b) { return (a + b - 1) / b; }
static inline long lcdiv(long a, long b) { return (a + b - 1) / b; }

__global__ void zero_kernel(float* __restrict__ p, int n) {
  int i = blockIdx.x * blockDim.x + threadIdx.x;
  if (i < n) p[i] = 0.f;
}

// ---- BN-stats: wave butterfly -> LDS -> 1 global atomic/block/channel ----
template<int COB, int COT>
__device__ inline void bn_stats_reduce(float (&acc)[COT], float* s_red,
                                       float* stats, int cb, int lane) {
  constexpr int TPR = COB / COT;
#pragma unroll
  for (int o = 0; o < COT; ++o) {
    float v = acc[o];
    float q = v * v;
#pragma unroll
    for (int off = 32; off >= TPR; off >>= 1) {
      v += __shfl_xor(v, off);
      q += __shfl_xor(q, off);
    }
    if (lane < TPR) {
      atomicAdd(&s_red[lane * COT + o], v);
      atomicAdd(&s_red[COB + lane * COT + o], q);
    }
  }
  __syncthreads();
  if ((int)threadIdx.x < COB) {
    atomicAdd(&stats[cb + threadIdx.x], s_red[threadIdx.x]);
    atomicAdd(&stats[64 + cb + threadIdx.x], s_red[COB + threadIdx.x]);
  }
}

// ---- cooperative stage of W cout-slice into LDS (padded k-stride) ----
template<int CI, int CO, int COB, int WSTRIDE>
__device__ inline void stage_weights(const float* __restrict__ w, float* sW, int cb) {
  constexpr int Q = COB / 4;
  for (int idx = threadIdx.x; idx < 27 * CI * Q; idx += 256) {
    int k = idx / (CI * Q);
    int r = idx - k * (CI * Q);
    int ci = r / Q;
    int oq = r - ci * Q;
    float4 v = *(const float4*)(w + ((long)k * CI + ci) * CO + cb + oq * 4);
    *(float4*)(&sW[k * WSTRIDE + ci * COB + oq * 4]) = v;
  }
}

// ---- full-27 k-loop (dense-ish levels). Weights from LDS (broadcast reads).
template<int CI, int CO, int COT, int COB>
__global__ __launch_bounds__(256) void conv_full(
    const float* __restrict__ f, const int* __restrict__ nbr,
    const float* __restrict__ w, float* __restrict__ y,
    float* __restrict__ stats, int nout) {
  constexpr int TPR = COB / COT;
  constexpr int F4 = CI / 4;
  constexpr int WSTRIDE = CI * COB + 4;
  __shared__ __align__(16) float sW[27 * WSTRIDE];
  __shared__ float s_red[2 * COB];
  const int cb = blockIdx.y * COB;

  stage_weights<CI, CO, COB, WSTRIDE>(w, sW, cb);
  for (int i = threadIdx.x; i < 2 * COB; i += 256) s_red[i] = 0.f;
  __syncthreads();

  const long t = (long)blockIdx.x * 256 + threadIdx.x;
  const int n = (int)(t / TPR);
  const int part = (int)(t % TPR);
  const int ob = part * COT;
  const int lane = threadIdx.x & 63;

  float acc[COT];
#pragma unroll
  for (int o = 0; o < COT; ++o) acc[o] = 0.f;

  if (n < nout) {
    const int* nb = nbr + (long)n * 27;
    int nbv[27];
#pragma unroll
    for (int k = 0; k < 27; ++k) nbv[k] = nb[k];

    float4 buf[F4], nbuf[F4];
    {
      const float4* fr = (const float4*)(f + (long)max(nbv[0], 0) * CI);
#pragma unroll
      for (int c = 0; c < F4; ++c) buf[c] = fr[c];
    }
#pragma unroll 1
    for (int k = 0; k < 27; ++k) {
      if (k + 1 < 27) {
        const float4* fr = (const float4*)(f + (long)max(nbv[k + 1], 0) * CI);
#pragma unroll
        for (int c = 0; c < F4; ++c) nbuf[c] = fr[c];
      }
      if (nbv[k] >= 0) {
        const float* wk = &sW[k * WSTRIDE + ob];
#pragma unroll
        for (int c = 0; c < F4; ++c) {
          float4 fv = buf[c];
#pragma unroll
          for (int j = 0; j < 4; ++j) {
            float fc = (j == 0) ? fv.x : (j == 1) ? fv.y : (j == 2) ? fv.z : fv.w;
            const float4* wr = (const float4*)(wk + (c * 4 + j) * COB);
#pragma unroll
            for (int o4 = 0; o4 < COT / 4; ++o4) {
              float4 wv = wr[o4];
              acc[o4 * 4 + 0] = fmaf(fc, wv.x, acc[o4 * 4 + 0]);
              acc[o4 * 4 + 1] = fmaf(fc, wv.y, acc[o4 * 4 + 1]);
              acc[o4 * 4 + 2] = fmaf(fc, wv.z, acc[o4 * 4 + 2]);
              acc[o4 * 4 + 3] = fmaf(fc, wv.w, acc[o4 * 4 + 3]);
            }
          }
        }
      }
      if (k + 1 < 27) {
#pragma unroll
        for (int c = 0; c < F4; ++c) buf[c] = nbuf[c];
      }
    }
    float* yr = y + (long)n * CO + cb + ob;
#pragma unroll
    for (int o4 = 0; o4 < COT / 4; ++o4)
      *(float4*)(yr + o4 * 4) =
          make_float4(acc[4 * o4], acc[4 * o4 + 1], acc[4 * o4 + 2], acc[4 * o4 + 3]);
  }
  bn_stats_reduce<COB, COT>(acc, s_red, stats, cb, lane);
}

// ---- compacted k-loop (sparse tables). Weights from LDS (divergent-k, padded).
template<int CI, int CO, int COT, int COB>
__global__ __launch_bounds__(256) void conv_compact(
    const float* __restrict__ f, const int* __restrict__ nbr,
    const float* __restrict__ w, float* __restrict__ y,
    float* __restrict__ stats, int nout) {
  constexpr int TPR = COB / COT;
  constexpr int F4 = CI / 4;
  constexpr int WSTRIDE = CI * COB + 4;
  __shared__ __align__(16) float sW[27 * WSTRIDE];
  __shared__ float s_red[2 * COB];
  const int cb = blockIdx.y * COB;

  stage_weights<CI, CO, COB, WSTRIDE>(w, sW, cb);
  for (int i = threadIdx.x; i < 2 * COB; i += 256) s_red[i] = 0.f;
  __syncthreads();

  const long t = (long)blockIdx.x * 256 + threadIdx.x;
  const int n = (int)(t / TPR);
  const int part = (int)(t % TPR);
  const int ob = part * COT;
  const int lane = threadIdx.x & 63;

  float acc[COT];
#pragma unroll
  for (int o = 0; o < COT; ++o) acc[o] = 0.f;

  if (n < nout) {
    const int* nb = nbr + (long)n * 27;
    int nbv[27];
    unsigned m = 0;
#pragma unroll
    for (int k = 0; k < 27; ++k) {
      nbv[k] = nb[k];
      m |= (nbv[k] >= 0 ? 1u : 0u) << k;
    }
    int k = -1;
    float4 buf[F4], nbuf[F4];
    if (m) {
      k = __builtin_ctz(m); m &= m - 1;
      const float4* fr = (const float4*)(f + (long)nbv[k] * CI);
#pragma unroll
      for (int c = 0; c < F4; ++c) buf[c] = fr[c];
    }
    while (k >= 0) {
      int k2 = -1;
      if (m) {
        k2 = __builtin_ctz(m); m &= m - 1;
        const float4* fr = (const float4*)(f + (long)nbv[k2] * CI);
#pragma unroll
        for (int c = 0; c < F4; ++c) nbuf[c] = fr[c];
      }
      const float* wk = &sW[k * WSTRIDE + ob];
#pragma unroll
      for (int c = 0; c < F4; ++c) {
        float4 fv = buf[c];
#pragma unroll
        for (int j = 0; j < 4; ++j) {
          float fc = (j == 0) ? fv.x : (j == 1) ? fv.y : (j == 2) ? fv.z : fv.w;
          const float4* wr = (const float4*)(wk + (c * 4 + j) * COB);
#pragma unroll
          for (int o4 = 0; o4 < COT / 4; ++o4) {
            float4 wv = wr[o4];
            acc[o4 * 4 + 0] = fmaf(fc, wv.x, acc[o4 * 4 + 0]);
            acc[o4 * 4 + 1] = fmaf(fc, wv.y, acc[o4 * 4 + 1]);
            acc[o4 * 4 + 2] = fmaf(fc, wv.z, acc[o4 * 4 + 2]);
            acc[o4 * 4 + 3] = fmaf(fc, wv.w, acc[o4 * 4 + 3]);
          }
        }
      }
      k = k2;
#pragma unroll
      for (int c = 0; c < F4; ++c) buf[c] = nbuf[c];
    }
    float* yr = y + (long)n * CO + cb + ob;
#pragma unroll
    for (int o4 = 0; o4 < COT / 4; ++o4)
      *(float4*)(yr + o4 * 4) =
          make_float4(acc[4 * o4], acc[4 * o4 + 1], acc[4 * o4 + 2], acc[4 * o4 + 3]);
  }
  bn_stats_reduce<COB, COT>(acc, s_red, stats, cb, lane);
}

// Applies training-mode BN (+ ReLU) and optional residual add (skip != nullptr).
template<int CO>
__global__ __launch_bounds__(256) void bn_relu_kernel(
    const float* __restrict__ y, const float* __restrict__ stats,
    const float* __restrict__ g, const float* __restrict__ b,
    const float* __restrict__ skip, float* __restrict__ out, int nout) {
  int i = blockIdx.x * blockDim.x + threadIdx.x;
  int total = nout * CO;
  if (i >= total) return;
  int o = i % CO;
  float inv_n = 1.f / (float)nout;
  float mu = stats[o] * inv_n;
  float var = stats[64 + o] * inv_n - mu * mu;
  float v = (y[i] - mu) * rsqrtf(var + EPSV) * g[o] + b[o];
  v = fmaxf(v, 0.f);
  if (skip) v += skip[i];
  out[i] = v;
}

// out[n,j] = sum_c x[n,c] * w[j,c]   (8x8)
__global__ __launch_bounds__(256) void linear_kernel(
    const float* __restrict__ x, const float* __restrict__ w,
    float* __restrict__ out, int n0) {
  int i = blockIdx.x * blockDim.x + threadIdx.x;
  if (i >= n0 * 8) return;
  int n = i >> 3, j = i & 7;
  const float* xr = x + n * 8;
  const float* wr = w + j * 8;
  float acc = 0.f;
#pragma unroll
  for (int c = 0; c < 8; ++c) acc = fmaf(xr[c], wr[c], acc);
  out[i] = acc;
}

extern "C" void kernel_launch(void* const* d_in, const int* in_sizes, int n_in,
                              void* d_out, int out_size, void* d_ws, size_t ws_size,
                              hipStream_t stream) {
  // ---- inputs (setup_inputs dict order) ----
  const float* feats   = (const float*)d_in[0];
  const int* nbr0      = (const int*)d_in[1];
  const int* nbr_d01   = (const int*)d_in[2];
  const int* nbr1      = (const int*)d_in[3];
  const int* nbr_d12   = (const int*)d_in[4];
  const int* nbr2      = (const int*)d_in[5];
  const int* nbr_d23   = (const int*)d_in[6];
  const int* nbr3      = (const int*)d_in[7];
  const int* nbr_u32   = (const int*)d_in[8];
  const int* nbr_u21   = (const int*)d_in[9];
  const int* nbr_u10   = (const int*)d_in[10];
  const float* w[10];
  const float* g[10];
  const float* b[10];
  for (int i = 0; i < 10; ++i) {
    w[i] = (const float*)d_in[11 + 3 * i];
    g[i] = (const float*)d_in[12 + 3 * i];
    b[i] = (const float*)d_in[13 + 3 * i];
  }
  const float* lin_w = (const float*)d_in[41];

  const int N0 = in_sizes[0] / 16;
  const int N1 = in_sizes[2] / 27;
  const int N2 = in_sizes[4] / 27;
  const int N3 = in_sizes[6] / 27;

  // ---- workspace layout (floats) ----
  float* ws    = (float*)d_ws;
  float* stats = ws;                       // 10 slots x 128 floats
  float* c0f   = stats + 10 * 128;         // N0*8   (skip, kept)
  float* t1    = c0f + (size_t)N0 * 8;     // N1*16
  float* c2f   = t1 + (size_t)N1 * 16;     // N1*16  (skip, kept)
  float* t2    = c2f + (size_t)N1 * 16;    // N2*32
  float* c4f   = t2 + (size_t)N2 * 32;     // N2*32  (skip, kept)
  float* t3    = c4f + (size_t)N2 * 32;    // N3*64
  float* t4    = t3 + (size_t)N3 * 64;     // N3*64
  float* t5    = t2;                       // reuse (t2 dead after conv4)
  float* t6    = t1;                       // reuse (t1 dead after conv2)

  float* out0 = (float*)d_out;                  // linear output; also conv9 y staging
  float* x0   = (float*)d_out + (size_t)N0 * 8; // second output: x itself

  zero_kernel<<<cdiv(10 * 128, 256), 256, 0, stream>>>(stats, 10 * 128);

  // conv0: 16->8 @ N0 (level-0 sparse) -> compact, COT=8, COB=8
  conv_compact<16, 8, 8, 8><<<dim3((int)lcdiv((long)N0, 256), 1), 256, 0, stream>>>(
      feats, nbr0, w[0], c0f, stats + 0 * 128, N0);
  bn_relu_kernel<8><<<cdiv(N0 * 8, 256), 256, 0, stream>>>(c0f, stats + 0 * 128, g[0], b[0], nullptr, c0f, N0);

  // conv1: 8->16 down to N1 (gathers sparse level-0) -> compact, COT=8, COB=16
  conv_compact<8, 16, 8, 16><<<dim3((int)lcdiv((long)N1 * 2, 256), 1), 256, 0, stream>>>(
      c0f, nbr_d01, w[1], t1, stats + 1 * 128, N1);
  bn_relu_kernel<16><<<cdiv(N1 * 16, 256), 256, 0, stream>>>(t1, stats + 1 * 128, g[1], b[1], nullptr, t1, N1);

  // conv2: 16->16 @ N1 -> full, COT=8, COB=16
  conv_full<16, 16, 8, 16><<<dim3((int)lcdiv((long)N1 * 2, 256), 1), 256, 0, stream>>>(
      t1, nbr1, w[2], c2f, stats + 2 * 128, N1);
  bn_relu_kernel<16><<<cdiv(N1 * 16, 256), 256, 0, stream>>>(c2f, stats + 2 * 128, g[2], b[2], nullptr, c2f, N1);

  // conv3: 16->32 down to N2 -> full, COT=8, COB=16, y=2
  conv_full<16, 32, 8, 16><<<dim3((int)lcdiv((long)N2 * 2, 256), 2), 256, 0, stream>>>(
      c2f, nbr_d12, w[3], t2, stats + 3 * 128, N2);
  bn_relu_kernel<32><<<cdiv(N2 * 32, 256), 256, 0, stream>>>(t2, stats + 3 * 128, g[3], b[3], nullptr, t2, N2);

  // conv4: 32->32 @ N2 -> full, COT=8, COB=16, y=2
  conv_full<32, 32, 8, 16><<<dim3((int)lcdiv((long)N2 * 2, 256), 2), 256, 0, stream>>>(
      t2, nbr2, w[4], c4f, stats + 4 * 128, N2);
  bn_relu_kernel<32><<<cdiv(N2 * 32, 256), 256, 0, stream>>>(c4f, stats + 4 * 128, g[4], b[4], nullptr, c4f, N2);

  // conv5: 32->64 down to N3 -> full, COT=4, COB=16, y=4
  conv_full<32, 64, 4, 16><<<dim3((int)lcdiv((long)N3 * 4, 256), 4), 256, 0, stream>>>(
      c4f, nbr_d23, w[5], t3, stats + 5 * 128, N3);
  bn_relu_kernel<64><<<cdiv(N3 * 64, 256), 256, 0, stream>>>(t3, stats + 5 * 128, g[5], b[5], nullptr, t3, N3);

  // conv6: 64->64 @ N3 -> full, COT=4, COB=16, y=4
  conv_full<64, 64, 4, 16><<<dim3((int)lcdiv((long)N3 * 4, 256), 4), 256, 0, stream>>>(
      t3, nbr3, w[6], t4, stats + 6 * 128, N3);
  bn_relu_kernel<64><<<cdiv(N3 * 64, 256), 256, 0, stream>>>(t4, stats + 6 * 128, g[6], b[6], nullptr, t4, N3);

  // conv7: 64->32 up to N2 (parity-sparse) -> compact, COT=8, COB=8, y=4
  conv_compact<64, 32, 8, 8><<<dim3((int)lcdiv((long)N2, 256), 4), 256, 0, stream>>>(
      t4, nbr_u32, w[7], t5, stats + 7 * 128, N2);
  bn_relu_kernel<32><<<cdiv(N2 * 32, 256), 256, 0, stream>>>(t5, stats + 7 * 128, g[7], b[7], c4f, t5, N2);

  // conv8: 32->16 up to N1 (parity-sparse) -> compact, COT=8, COB=16
  conv_compact<32, 16, 8, 16><<<dim3((int)lcdiv((long)N1 * 2, 256), 1), 256, 0, stream>>>(
      t5, nbr_u21, w[8], t6, stats + 8 * 128, N1);
  bn_relu_kernel<16><<<cdiv(N1 * 16, 256), 256, 0, stream>>>(t6, stats + 8 * 128, g[8], b[8], c2f, t6, N1);

  // conv9: 16->8 up to N0 (parity-sparse) -> compact, COT=8, COB=8
  conv_compact<16, 8, 8, 8><<<dim3((int)lcdiv((long)N0, 256), 1), 256, 0, stream>>>(
      t6, nbr_u10, w[9], out0, stats + 9 * 128, N0);
  bn_relu_kernel<8><<<cdiv(N0 * 8, 256), 256, 0, stream>>>(out0, stats + 9 * 128, g[9], b[9], c0f, x0, N0);

  // final linear: out0 = x0 @ lin_w.T
  linear_kernel<<<cdiv(N0 * 8, 256), 256, 0, stream>>>(x0, lin_w, out0, N0);
}